// Round 2
// baseline (1977.913 us; speedup 1.0000x reference)
//
#include <hip/hip_runtime.h>
#include <hip/hip_bf16.h>
#include <math.h>

// Problem constants
#define N_ROUTES 7
#define PC_DIM   512
#define MC_DIM   128
#define KCLS     25
#define BATCH    4096

#define ROW_IN   (N_ROUTES * PC_DIM)          // 3584 floats per batch row of prim_pose
#define JDIM     (KCLS * MC_DIM)              // 3200 vote cols per route
#define VOTE_B   (N_ROUTES * JDIM)            // 22400 floats of vote per batch elem

// ---------------- Kernel 1: vote GEMM (per-route SGEMM) ----------------
// C_n[b, j] = sum_d pose[b, n, d] * w[n, d, j],  j = m*128 + v
// Tile: BM=128, BN=128, BK=16; 256 threads; 8x8 micro-tile per thread.
// Row-guarded so the batch chunk need not be a multiple of BM.
#define BM 128
#define BN 128
#define BK 16
#define LDP 132   // padded leading dim for LDS tiles (16B-aligned rows)

__global__ __launch_bounds__(256) void vote_gemm(const float* __restrict__ pose,
                                                 const float* __restrict__ w,
                                                 float* __restrict__ vote,
                                                 int rows) {
    const int n  = blockIdx.z;
    const int m0 = blockIdx.y * BM;   // batch-row tile (within chunk)
    const int j0 = blockIdx.x * BN;   // output-col tile (within route)

    __shared__ float As[BK][LDP];     // A transposed: As[k][m]
    __shared__ float Bs[BK][LDP];     // Bs[k][j]

    const int tid = threadIdx.x;
    const int tx = tid & 15;          // 0..15 -> cols
    const int ty = tid >> 4;          // 0..15 -> rows

    float acc[8][8];
#pragma unroll
    for (int r = 0; r < 8; r++)
#pragma unroll
        for (int c = 0; c < 8; c++) acc[r][c] = 0.f;

    const float* Ab = pose + (size_t)n * PC_DIM;
    const float* Wb = w + (size_t)n * PC_DIM * JDIM;

    for (int k0 = 0; k0 < PC_DIM; k0 += BK) {
        // Load A tile: 128 rows x 16 cols, transposed into As[k][m]
        {
            int f = tid;
#pragma unroll
            for (int i = 0; i < 2; i++, f += 256) {
                int row = m0 + (f >> 2);     // global row within chunk
                if (row >= rows) row = rows - 1;   // clamp (in-bounds, result discarded)
                int c4  = (f & 3) * 4;       // 0,4,8,12
                const float4 v = *(const float4*)(Ab + (size_t)row * ROW_IN + k0 + c4);
                int lr = f >> 2;
                As[c4 + 0][lr] = v.x;
                As[c4 + 1][lr] = v.y;
                As[c4 + 2][lr] = v.z;
                As[c4 + 3][lr] = v.w;
            }
        }
        // Load B tile: 16 rows x 128 cols
        {
            int f = tid;
#pragma unroll
            for (int i = 0; i < 2; i++, f += 256) {
                int row = f >> 5;            // 0..15
                int c4  = (f & 31) * 4;      // 0..124
                *(float4*)(&Bs[row][c4]) = *(const float4*)(Wb + (size_t)(k0 + row) * JDIM + j0 + c4);
            }
        }
        __syncthreads();

#pragma unroll
        for (int kk = 0; kk < BK; kk++) {
            float a[8], bfr[8];
            *(float4*)(a)     = *(const float4*)(&As[kk][ty * 4]);
            *(float4*)(a + 4) = *(const float4*)(&As[kk][64 + ty * 4]);
            *(float4*)(bfr)     = *(const float4*)(&Bs[kk][tx * 4]);
            *(float4*)(bfr + 4) = *(const float4*)(&Bs[kk][64 + tx * 4]);
#pragma unroll
            for (int r = 0; r < 8; r++)
#pragma unroll
                for (int c = 0; c < 8; c++) acc[r][c] += a[r] * bfr[c];
        }
        __syncthreads();
    }

    // Write C: vote[brow*22400 + n*3200 + j], guarded by rows
    float* Cb = vote + (size_t)n * JDIM + j0;
#pragma unroll
    for (int r = 0; r < 8; r++) {
        int row = m0 + ((r < 4) ? (ty * 4 + r) : (64 + ty * 4 + (r - 4)));
        if (row >= rows) continue;
        float* cp = Cb + (size_t)row * VOTE_B;
        float4 v0 = {acc[r][0], acc[r][1], acc[r][2], acc[r][3]};
        float4 v1 = {acc[r][4], acc[r][5], acc[r][6], acc[r][7]};
        *(float4*)(cp + tx * 4)      = v0;
        *(float4*)(cp + 64 + tx * 4) = v1;
    }
}

// ---------------- Kernel 2: fused routing (one block per batch elem) ----------------
__device__ inline float wave_reduce_sum(float v) {
#pragma unroll
    for (int off = 32; off; off >>= 1) v += __shfl_xor(v, off, 64);
    return v;
}

__global__ __launch_bounds__(256) void routing_kernel(
        const float* __restrict__ vote,   // [chunk,7,25,128]
        const float* __restrict__ act,    // [chunk,7]   (pre-offset)
        const float* __restrict__ gamma,  // [128]
        const float* __restrict__ beta,   // [128]
        const float* __restrict__ emb,    // [25,128]
        const float* __restrict__ bias,   // [25]
        float* __restrict__ out_logits,   // [chunk,25]  (pre-offset)
        float* __restrict__ out_act,      // [chunk,7]   (pre-offset)
        float* __restrict__ out_coef) {   // [chunk,7,25](pre-offset)
    const int b = blockIdx.x;
    __shared__ float vote_s[VOTE_B];             // 89600 B
    __shared__ float pose_s[KCLS * MC_DIM];      // 12800 B
    __shared__ float coef_s[N_ROUTES * KCLS];    // 700 B
    __shared__ float act_s[N_ROUTES];

    const int tid  = threadIdx.x;
    const int lane = tid & 63;
    const int wave = tid >> 6;                   // 0..3

    // Stage vote[b] into LDS (contiguous float4)
    {
        const float4* src = (const float4*)(vote + (size_t)b * VOTE_B);
        float4* dst = (float4*)vote_s;
        for (int i = tid; i < VOTE_B / 4; i += 256) dst[i] = src[i];
    }
    if (tid < N_ROUTES) {
        float a = act[(size_t)b * N_ROUTES + tid];
        act_s[tid] = a;
        out_act[(size_t)b * N_ROUTES + tid] = a;
    }
    const float g0  = gamma[lane],      g1  = gamma[lane + 64];
    const float be0 = beta[lane],       be1 = beta[lane + 64];
    __syncthreads();

    const float scale = 0.088388347648318447f;   // 1/sqrt(128)

    auto update_pose = [&](bool first) {
        for (int m = wave; m < KCLS; m += 4) {
            float r0 = 0.f, r1 = 0.f;
#pragma unroll
            for (int n = 0; n < N_ROUTES; n++) {
                float c = first ? (act_s[n] * 0.04f) : (coef_s[n * KCLS + m] * act_s[n]);
                r0 += c * vote_s[n * JDIM + m * MC_DIM + lane];
                r1 += c * vote_s[n * JDIM + m * MC_DIM + lane + 64];
            }
            float s  = wave_reduce_sum(r0 + r1);
            float sq = wave_reduce_sum(r0 * r0 + r1 * r1);
            float mean = s * (1.0f / 128.0f);
            float var  = sq * (1.0f / 128.0f) - mean * mean;
            float rs   = rsqrtf(var + 1e-5f);
            pose_s[m * MC_DIM + lane]      = (r0 - mean) * rs * g0 + be0;
            pose_s[m * MC_DIM + lane + 64] = (r1 - mean) * rs * g1 + be1;
        }
        __syncthreads();
    };

    // iteration 0: uniform coefficients (1/25 each)
    update_pose(true);

    // iterations 1, 2
    for (int it = 1; it < 3; it++) {
        for (int p = wave; p < N_ROUTES * KCLS; p += 4) {
            int n = p / KCLS, m = p % KCLS;
            float d = vote_s[n * JDIM + m * MC_DIM + lane]      * pose_s[m * MC_DIM + lane]
                    + vote_s[n * JDIM + m * MC_DIM + lane + 64] * pose_s[m * MC_DIM + lane + 64];
            d = wave_reduce_sum(d);
            if (lane == 0) coef_s[p] = d * scale;
        }
        __syncthreads();
        if (tid < N_ROUTES) {
            float mx = -1e30f;
            for (int m = 0; m < KCLS; m++) mx = fmaxf(mx, coef_s[tid * KCLS + m]);
            float s = 0.f;
            float e[KCLS];
            for (int m = 0; m < KCLS; m++) { e[m] = expf(coef_s[tid * KCLS + m] - mx); s += e[m]; }
            float inv = 1.0f / s;
            for (int m = 0; m < KCLS; m++) coef_s[tid * KCLS + m] = e[m] * inv;
        }
        __syncthreads();
        update_pose(false);
    }

    // logits[b,m] = <pose[m,:], emb[m,:]> + bias[m]
    for (int m = wave; m < KCLS; m += 4) {
        float d = pose_s[m * MC_DIM + lane]      * emb[m * MC_DIM + lane]
                + pose_s[m * MC_DIM + lane + 64] * emb[m * MC_DIM + lane + 64];
        d = wave_reduce_sum(d);
        if (lane == 0) out_logits[(size_t)b * KCLS + m] = d + bias[m];
    }
    if (tid < N_ROUTES * KCLS) out_coef[(size_t)b * (N_ROUTES * KCLS) + tid] = coef_s[tid];
}

// ---------------- launch ----------------
extern "C" void kernel_launch(void* const* d_in, const int* in_sizes, int n_in,
                              void* d_out, int out_size, void* d_ws, size_t ws_size,
                              hipStream_t stream) {
    const float* pose  = (const float*)d_in[0];   // [4096,7,512]
    const float* act   = (const float*)d_in[1];   // [4096,7]
    const float* w     = (const float*)d_in[2];   // [7,512,25,128]
    const float* gamma = (const float*)d_in[3];   // [128]
    const float* beta  = (const float*)d_in[4];   // [128]
    const float* emb   = (const float*)d_in[5];   // [25,128]
    const float* bias  = (const float*)d_in[6];   // [25]

    float* out        = (float*)d_out;
    float* out_logits = out;                                    // 4096*25
    float* out_act    = out + BATCH * KCLS;                     // 4096*7
    float* out_coef   = out + BATCH * KCLS + BATCH * N_ROUTES;  // 4096*7*25

    float* vote = (float*)d_ws;

    // Size the batch chunk to the workspace we actually have.
    const size_t bytes_per_row = (size_t)VOTE_B * sizeof(float);   // 89,600 B
    size_t cap = ws_size / bytes_per_row;
    int chunk;
    if (cap >= (size_t)BATCH)      chunk = BATCH;
    else if (cap >= 128)           chunk = (int)(cap & ~(size_t)127);  // multiple of 128
    else if (cap >= 16)            chunk = (int)(cap & ~(size_t)15);   // multiple of 16
    else                           chunk = (int)(cap > 0 ? cap : 1);   // last resort

    for (int b0 = 0; b0 < BATCH; b0 += chunk) {
        int rows = BATCH - b0 < chunk ? BATCH - b0 : chunk;
        dim3 g1(JDIM / BN, (rows + BM - 1) / BM, N_ROUTES);
        vote_gemm<<<g1, 256, 0, stream>>>(pose + (size_t)b0 * ROW_IN, w, vote, rows);
        routing_kernel<<<rows, 256, 0, stream>>>(
            vote,
            act + (size_t)b0 * N_ROUTES,
            gamma, beta, emb, bias,
            out_logits + (size_t)b0 * KCLS,
            out_act    + (size_t)b0 * N_ROUTES,
            out_coef   + (size_t)b0 * N_ROUTES * KCLS);
    }
}

// Round 4
// 734.276 us; speedup vs baseline: 2.6937x; 2.6937x over previous
//
#include <hip/hip_runtime.h>
#include <hip/hip_bf16.h>
#include <math.h>

// Problem constants
#define N_ROUTES 7
#define PC_DIM   512
#define MC_DIM   128
#define KCLS     25
#define BATCH    4096

#define ROW_IN   (N_ROUTES * PC_DIM)          // 3584 elems per batch row of pose
#define JDIM     (KCLS * MC_DIM)              // 3200 vote cols per route
#define VOTE_B   (N_ROUTES * JDIM)            // 22400 vote elems per batch elem

typedef __attribute__((ext_vector_type(8))) _Float16 half8;
typedef __attribute__((ext_vector_type(4))) float f32x4;

__device__ inline ushort f2h(float f) {
    _Float16 h = (_Float16)f;
    return __builtin_bit_cast(ushort, h);
}

__device__ inline void load_lds16(const void* g, void* l) {
    __builtin_amdgcn_global_load_lds(
        (const __attribute__((address_space(1))) void*)g,
        (__attribute__((address_space(3))) void*)l, 16, 0, 0);
}

// ---------------- conversion kernels ----------------
// pose fp32 [B,7,512] -> fp16 same layout. 8 elems/thread.
__global__ __launch_bounds__(256) void conv_pose(const float* __restrict__ p,
                                                 ushort* __restrict__ pb, int n8) {
    int i = blockIdx.x * 256 + threadIdx.x;
    if (i >= n8) return;
    const float4* s = (const float4*)p + (size_t)i * 2;
    float4 a = s[0], b = s[1];
    ushort t[8];
    t[0]=f2h(a.x); t[1]=f2h(a.y); t[2]=f2h(a.z); t[3]=f2h(a.w);
    t[4]=f2h(b.x); t[5]=f2h(b.y); t[6]=f2h(b.z); t[7]=f2h(b.w);
    *(uint4*)(pb + (size_t)i * 8) = *(uint4*)t;
}

// w fp32 [7][512][3200] -> wt fp16 [7][3200][512] (transposed per route)
__global__ __launch_bounds__(256) void conv_w(const float* __restrict__ w,
                                              ushort* __restrict__ wt) {
    __shared__ float t[32][33];
    const int j0 = blockIdx.x * 32, d0 = blockIdx.y * 32, r = blockIdx.z;
    const int c = threadIdx.x & 31, rr = threadIdx.x >> 5;   // 8 rows/pass
    const float* wp = w + (size_t)r * PC_DIM * JDIM;
#pragma unroll
    for (int i = 0; i < 4; i++)
        t[rr + i * 8][c] = wp[(size_t)(d0 + rr + i * 8) * JDIM + j0 + c];
    __syncthreads();
    ushort* op = wt + (size_t)r * JDIM * PC_DIM;
#pragma unroll
    for (int i = 0; i < 4; i++)
        op[(size_t)(j0 + rr + i * 8) * PC_DIM + d0 + c] = f2h(t[c][rr + i * 8]);
}

// ---------------- Kernel 1: MFMA vote GEMM (fp16 in, fp32 out) ----------------
// C[b, j] = sum_k poseb[b, route, k] * wt[route, j, k]
// 128x128 tile, BK=32, 4 waves (2x2), each wave 4x4 of 16x16x32 MFMA.
#define GBM 128
#define GBN 128
#define GBK 32

__global__ __launch_bounds__(256) void vote_gemm_mfma(
        const ushort* __restrict__ poseb,  // [rows][3584] fp16
        const ushort* __restrict__ wt,     // [7][3200][512] fp16
        float* __restrict__ vote,          // [rows][7][3200] fp32
        int rows) {
    const int route = blockIdx.z;
    const int b0 = blockIdx.y * GBM;
    const int j0 = blockIdx.x * GBN;

    // 16KB staging (As 8KB + Bs 8KB); epilogue overlays 17,408B
    __shared__ __align__(16) char smem[4 * 16 * 68 * 4];
    ushort* As = (ushort*)smem;          // 4096 fp16, chunks [row*4 + swizzled q] x 8
    ushort* Bs = As + GBM * GBK;

    const int tid = threadIdx.x;
    const int l = tid & 63, w = tid >> 6;
    const int wm = w >> 1, wn = w & 1;

    f32x4 acc[4][4] = {};

    const ushort* Aptr = poseb + (size_t)route * PC_DIM;
    const ushort* Bptr = wt + (size_t)route * JDIM * PC_DIM;

    const int q = l >> 4;
    const int swzl = ((l & 15) >> 1) & 3;

    for (int k0 = 0; k0 < PC_DIM; k0 += GBK) {
        // stage A and B: thread f covers LDS chunk f (lane-contiguous for global_load_lds),
        // global k-segment = (f&3) ^ swz(row) so fragment reads are conflict-free.
        int f = tid;
#pragma unroll
        for (int i = 0; i < 2; i++, f += 256) {
            const int row = f >> 2;
            const int qg = (f & 3) ^ ((row >> 1) & 3);
            int ga = b0 + row; if (ga >= rows) ga = rows - 1;
            load_lds16(Aptr + (size_t)ga * ROW_IN + k0 + qg * 8, As + (size_t)f * 8);
            load_lds16(Bptr + (size_t)(j0 + row) * PC_DIM + k0 + qg * 8, Bs + (size_t)f * 8);
        }
        __syncthreads();

        half8 af[4], bfg[4];
#pragma unroll
        for (int t = 0; t < 4; t++) {
            const int rowA = wm * 64 + t * 16 + (l & 15);
            const int rowB = wn * 64 + t * 16 + (l & 15);
            af[t]  = *(const half8*)(As + (size_t)(rowA * 4 + (q ^ swzl)) * 8);
            bfg[t] = *(const half8*)(Bs + (size_t)(rowB * 4 + (q ^ swzl)) * 8);
        }
#pragma unroll
        for (int mt = 0; mt < 4; mt++)
#pragma unroll
            for (int nt = 0; nt < 4; nt++)
                acc[mt][nt] = __builtin_amdgcn_mfma_f32_16x16x32_f16(
                    af[mt], bfg[nt], acc[mt][nt], 0, 0, 0);
        __syncthreads();
    }

    // Epilogue: per-wave LDS transpose (C layout -> row-major), fp32 float4 stores.
    float* ep = (float*)smem + w * 16 * 68;   // per-wave [16][68] fp32
    const int erow = l >> 2;                  // 0..15
    const int ec0  = (l & 3) * 16;            // 0,16,32,48
#pragma unroll
    for (int mt = 0; mt < 4; mt++) {
#pragma unroll
        for (int nt = 0; nt < 4; nt++)
#pragma unroll
            for (int i = 0; i < 4; i++)
                ep[((l >> 4) * 4 + i) * 68 + nt * 16 + (l & 15)] = acc[mt][nt][i];
        __syncthreads();
        const int grow = b0 + wm * 64 + mt * 16 + erow;
        if (grow < rows) {
            float* dst = vote + (size_t)grow * VOTE_B + route * JDIM + j0 + wn * 64 + ec0;
#pragma unroll
            for (int t8 = 0; t8 < 4; t8++)
                *(float4*)(dst + t8 * 4) = *(const float4*)&ep[erow * 68 + ec0 + t8 * 4];
        }
        __syncthreads();
    }
}

// ---------------- Kernel 2: fused routing (fp32 votes in registers) ----------------
__device__ inline float wave_reduce_sum(float v) {
#pragma unroll
    for (int off = 32; off; off >>= 1) v += __shfl_xor(v, off, 64);
    return v;
}

__global__ __launch_bounds__(512) void routing_kernel(
        const float* __restrict__ vote,   // [chunk][7][25][128] fp32
        const float* __restrict__ act,    // (pre-offset)
        const float* __restrict__ gamma,
        const float* __restrict__ beta,
        const float* __restrict__ emb,    // [25,128]
        const float* __restrict__ bias,   // [25]
        float* __restrict__ out_logits,   // (pre-offset)
        float* __restrict__ out_act,
        float* __restrict__ out_coef) {
    const int b = blockIdx.x;
    __shared__ float coef_s[N_ROUTES * KCLS];
    __shared__ float act_s[8];

    const int tid = threadIdx.x, l = tid & 63, wv = tid >> 6;   // 8 waves

    if (tid < N_ROUTES) {
        float a = act[(size_t)b * N_ROUTES + tid];
        act_s[tid] = a;
        out_act[(size_t)b * N_ROUTES + tid] = a;
    }

    // Wave wv owns m = wv + 8*t (wave 0 additionally owns m=24).
    // Lane l holds dims (2l, 2l+1) of vote[n][m][:] for all 7 routes.
    float2 v[4][N_ROUTES];
    const float* vb = vote + (size_t)b * VOTE_B;
#pragma unroll
    for (int t = 0; t < 4; t++) {
        int m = wv + 8 * t;
        if (m < KCLS) {
#pragma unroll
            for (int n = 0; n < N_ROUTES; n++)
                v[t][n] = *(const float2*)(vb + (size_t)n * JDIM + m * MC_DIM + 2 * l);
        }
    }
    const float2 g2  = *(const float2*)(gamma + 2 * l);
    const float2 be2 = *(const float2*)(beta  + 2 * l);
    __syncthreads();   // act_s ready

    float2 pose[4];
    const float scale = 0.088388347648318447f;   // 1/sqrt(128)

    auto update_pose = [&](bool first) {
#pragma unroll
        for (int t = 0; t < 4; t++) {
            int m = wv + 8 * t;
            if (m >= KCLS) continue;
            float r0 = 0.f, r1 = 0.f;
#pragma unroll
            for (int n = 0; n < N_ROUTES; n++) {
                float c = first ? (act_s[n] * 0.04f) : (coef_s[n * KCLS + m] * act_s[n]);
                r0 += c * v[t][n].x;
                r1 += c * v[t][n].y;
            }
            float s  = wave_reduce_sum(r0 + r1);
            float sq = wave_reduce_sum(r0 * r0 + r1 * r1);
            float mean = s * 0.0078125f;
            float var  = sq * 0.0078125f - mean * mean;
            float rs   = rsqrtf(var + 1e-5f);
            pose[t].x = (r0 - mean) * rs * g2.x + be2.x;
            pose[t].y = (r1 - mean) * rs * g2.y + be2.y;
        }
    };

    update_pose(true);

    for (int it = 1; it < 3; it++) {
        // agreement (each wave writes only its own m entries)
#pragma unroll
        for (int t = 0; t < 4; t++) {
            int m = wv + 8 * t;
            if (m >= KCLS) continue;
#pragma unroll
            for (int n = 0; n < N_ROUTES; n++) {
                float d = v[t][n].x * pose[t].x + v[t][n].y * pose[t].y;
                d = wave_reduce_sum(d);
                if (l == 0) coef_s[n * KCLS + m] = d * scale;
            }
        }
        __syncthreads();
        // softmax over m per route (tiny)
        if (tid < N_ROUTES) {
            float mx = -1e30f;
            for (int m = 0; m < KCLS; m++) mx = fmaxf(mx, coef_s[tid * KCLS + m]);
            float s = 0.f;
            float e[KCLS];
            for (int m = 0; m < KCLS; m++) { e[m] = expf(coef_s[tid * KCLS + m] - mx); s += e[m]; }
            float inv = 1.0f / s;
            for (int m = 0; m < KCLS; m++) coef_s[tid * KCLS + m] = e[m] * inv;
        }
        __syncthreads();
        update_pose(false);
    }

    // logits[b,m] = <pose[m,:], emb[m,:]> + bias[m]
#pragma unroll
    for (int t = 0; t < 4; t++) {
        int m = wv + 8 * t;
        if (m >= KCLS) continue;
        float2 ev = *(const float2*)(emb + m * MC_DIM + 2 * l);
        float d = wave_reduce_sum(pose[t].x * ev.x + pose[t].y * ev.y);
        if (l == 0) out_logits[(size_t)b * KCLS + m] = d + bias[m];
    }
    if (tid < N_ROUTES * KCLS)
        out_coef[(size_t)b * (N_ROUTES * KCLS) + tid] = coef_s[tid];
}

// ---------------- launch ----------------
extern "C" void kernel_launch(void* const* d_in, const int* in_sizes, int n_in,
                              void* d_out, int out_size, void* d_ws, size_t ws_size,
                              hipStream_t stream) {
    const float* pose  = (const float*)d_in[0];
    const float* act   = (const float*)d_in[1];
    const float* w     = (const float*)d_in[2];
    const float* gamma = (const float*)d_in[3];
    const float* beta  = (const float*)d_in[4];
    const float* emb   = (const float*)d_in[5];
    const float* bias  = (const float*)d_in[6];

    float* out        = (float*)d_out;
    float* out_logits = out;
    float* out_act    = out + BATCH * KCLS;
    float* out_coef   = out + BATCH * KCLS + BATCH * N_ROUTES;

    // workspace layout: wt fp16 | poseb fp16 | vote fp32 (chunked)
    const size_t wt_bytes    = (size_t)N_ROUTES * JDIM * PC_DIM * 2;   // 22,937,600
    const size_t poseb_bytes = (size_t)BATCH * ROW_IN * 2;             // 29,360,128
    ushort* wt    = (ushort*)d_ws;
    ushort* poseb = (ushort*)((char*)d_ws + wt_bytes);
    float*  votef = (float*)((char*)d_ws + wt_bytes + poseb_bytes);

    size_t rem = ws_size > wt_bytes + poseb_bytes ? ws_size - wt_bytes - poseb_bytes : 0;
    size_t cap = rem / ((size_t)VOTE_B * 4);
    int chunk;
    if (cap >= (size_t)BATCH)  chunk = BATCH;
    else if (cap >= 128)       chunk = (int)(cap & ~(size_t)127);
    else                       chunk = (int)(cap > 0 ? cap : 1);

    conv_w<<<dim3(JDIM / 32, PC_DIM / 32, N_ROUTES), 256, 0, stream>>>(w, wt);
    const int n8 = BATCH * ROW_IN / 8;
    conv_pose<<<(n8 + 255) / 256, 256, 0, stream>>>(pose, poseb, n8);

    for (int b0 = 0; b0 < BATCH; b0 += chunk) {
        int rows = BATCH - b0 < chunk ? BATCH - b0 : chunk;
        dim3 g1(JDIM / GBN, (rows + GBM - 1) / GBM, N_ROUTES);
        vote_gemm_mfma<<<g1, 256, 0, stream>>>(poseb + (size_t)b0 * ROW_IN, wt, votef, rows);
        routing_kernel<<<rows, 512, 0, stream>>>(
            votef,
            act + (size_t)b0 * N_ROUTES,
            gamma, beta, emb, bias,
            out_logits + (size_t)b0 * KCLS,
            out_act    + (size_t)b0 * N_ROUTES,
            out_coef   + (size_t)b0 * N_ROUTES * KCLS);
    }
}

// Round 5
// 401.842 us; speedup vs baseline: 4.9221x; 1.8273x over previous
//
#include <hip/hip_runtime.h>
#include <hip/hip_bf16.h>
#include <math.h>

// Problem constants
#define N_ROUTES 7
#define PC_DIM   512
#define MC_DIM   128
#define KCLS     25
#define BATCH    4096

#define ROW_IN   (N_ROUTES * PC_DIM)          // 3584 elems per batch row of pose
#define JDIM     (KCLS * MC_DIM)              // 3200 vote cols per route
#define VOTE_B   (N_ROUTES * JDIM)            // 22400 vote elems per batch elem

typedef __attribute__((ext_vector_type(8))) _Float16 half8;
typedef __attribute__((ext_vector_type(4))) float f32x4;

__device__ inline ushort f2h(float f) {
    _Float16 h = (_Float16)f;
    return __builtin_bit_cast(ushort, h);
}

__device__ inline float2 h2f2(uint u) {
    union { uint x; _Float16 h[2]; } c; c.x = u;
    return make_float2((float)c.h[0], (float)c.h[1]);
}

__device__ inline void load_lds16(const void* g, void* l) {
    __builtin_amdgcn_global_load_lds(
        (const __attribute__((address_space(1))) void*)g,
        (__attribute__((address_space(3))) void*)l, 16, 0, 0);
}

// ---------------- conversion kernels ----------------
__global__ __launch_bounds__(256) void conv_pose(const float* __restrict__ p,
                                                 ushort* __restrict__ pb, int n8) {
    int i = blockIdx.x * 256 + threadIdx.x;
    if (i >= n8) return;
    const float4* s = (const float4*)p + (size_t)i * 2;
    float4 a = s[0], b = s[1];
    ushort t[8];
    t[0]=f2h(a.x); t[1]=f2h(a.y); t[2]=f2h(a.z); t[3]=f2h(a.w);
    t[4]=f2h(b.x); t[5]=f2h(b.y); t[6]=f2h(b.z); t[7]=f2h(b.w);
    *(uint4*)(pb + (size_t)i * 8) = *(uint4*)t;
}

// w fp32 [7][512][3200] -> wt fp16 [7][3200][512] (transposed per route)
__global__ __launch_bounds__(256) void conv_w(const float* __restrict__ w,
                                              ushort* __restrict__ wt) {
    __shared__ float t[32][33];
    const int j0 = blockIdx.x * 32, d0 = blockIdx.y * 32, r = blockIdx.z;
    const int c = threadIdx.x & 31, rr = threadIdx.x >> 5;
    const float* wp = w + (size_t)r * PC_DIM * JDIM;
#pragma unroll
    for (int i = 0; i < 4; i++)
        t[rr + i * 8][c] = wp[(size_t)(d0 + rr + i * 8) * JDIM + j0 + c];
    __syncthreads();
    ushort* op = wt + (size_t)r * JDIM * PC_DIM;
#pragma unroll
    for (int i = 0; i < 4; i++)
        op[(size_t)(j0 + rr + i * 8) * PC_DIM + d0 + c] = f2h(t[c][rr + i * 8]);
}

// ---------------- Kernel 1: MFMA vote GEMM (fp16 in, fp16 out) ----------------
#define GBM 128
#define GBN 128
#define GBK 32

__global__ __launch_bounds__(256) void vote_gemm_mfma(
        const ushort* __restrict__ poseb,  // [rows][3584] fp16
        const ushort* __restrict__ wt,     // [7][3200][512] fp16
        ushort* __restrict__ vote,         // [rows][7][3200] fp16
        int rows) {
    const int route = blockIdx.z;
    const int b0 = blockIdx.y * GBM;
    const int j0 = blockIdx.x * GBN;

    __shared__ __align__(16) char smem[4 * 16 * 68 * 4];
    ushort* As = (ushort*)smem;
    ushort* Bs = As + GBM * GBK;

    const int tid = threadIdx.x;
    const int l = tid & 63, w = tid >> 6;
    const int wm = w >> 1, wn = w & 1;

    f32x4 acc[4][4] = {};

    const ushort* Aptr = poseb + (size_t)route * PC_DIM;
    const ushort* Bptr = wt + (size_t)route * JDIM * PC_DIM;

    const int q = l >> 4;
    const int swzl = ((l & 15) >> 1) & 3;

    for (int k0 = 0; k0 < PC_DIM; k0 += GBK) {
        int f = tid;
#pragma unroll
        for (int i = 0; i < 2; i++, f += 256) {
            const int row = f >> 2;
            const int qg = (f & 3) ^ ((row >> 1) & 3);
            int ga = b0 + row; if (ga >= rows) ga = rows - 1;
            load_lds16(Aptr + (size_t)ga * ROW_IN + k0 + qg * 8, As + (size_t)f * 8);
            load_lds16(Bptr + (size_t)(j0 + row) * PC_DIM + k0 + qg * 8, Bs + (size_t)f * 8);
        }
        __syncthreads();

        half8 af[4], bfg[4];
#pragma unroll
        for (int t = 0; t < 4; t++) {
            const int rowA = wm * 64 + t * 16 + (l & 15);
            const int rowB = wn * 64 + t * 16 + (l & 15);
            af[t]  = *(const half8*)(As + (size_t)(rowA * 4 + (q ^ swzl)) * 8);
            bfg[t] = *(const half8*)(Bs + (size_t)(rowB * 4 + (q ^ swzl)) * 8);
        }
#pragma unroll
        for (int mt = 0; mt < 4; mt++)
#pragma unroll
            for (int nt = 0; nt < 4; nt++)
                acc[mt][nt] = __builtin_amdgcn_mfma_f32_16x16x32_f16(
                    af[mt], bfg[nt], acc[mt][nt], 0, 0, 0);
        __syncthreads();
    }

    // Epilogue: per-wave LDS transpose, convert to fp16, 32B/lane stores.
    float* ep = (float*)smem + w * 16 * 68;
    const int erow = l >> 2;
    const int ec0  = (l & 3) * 16;
#pragma unroll
    for (int mt = 0; mt < 4; mt++) {
#pragma unroll
        for (int nt = 0; nt < 4; nt++)
#pragma unroll
            for (int i = 0; i < 4; i++)
                ep[((l >> 4) * 4 + i) * 68 + nt * 16 + (l & 15)] = acc[mt][nt][i];
        __syncthreads();
        const int grow = b0 + wm * 64 + mt * 16 + erow;
        if (grow < rows) {
            ushort t16[16];
#pragma unroll
            for (int t8 = 0; t8 < 4; t8++) {
                float4 v = *(float4*)&ep[erow * 68 + ec0 + t8 * 4];
                t16[t8*4+0]=f2h(v.x); t16[t8*4+1]=f2h(v.y);
                t16[t8*4+2]=f2h(v.z); t16[t8*4+3]=f2h(v.w);
            }
            ushort* dst = vote + (size_t)grow * VOTE_B + route * JDIM + j0 + wn * 64 + ec0;
            ((uint4*)dst)[0] = ((uint4*)t16)[0];
            ((uint4*)dst)[1] = ((uint4*)t16)[1];
        }
        __syncthreads();
    }
}

// ---------------- Kernel 2: fused routing ----------------
// Block = one batch elem, 512 threads (8 waves). Lane decomposition:
//   sub = l&15 -> v-dims [8*sub, 8*sub+8);  mg = l>>4;  m = wv + 8*mg.
// Each lane owns 8 dims of one decision capsule m -> reductions are 4-step
// shfl over 16 lanes; each wave processes 4 m's in parallel lane-groups.
__global__ __launch_bounds__(512) void routing_kernel(
        const ushort* __restrict__ vote16,  // [chunk][7][25][128] fp16
        const float* __restrict__ act,      // (pre-offset)
        const float* __restrict__ gamma,
        const float* __restrict__ beta,
        const float* __restrict__ emb,      // [25,128]
        const float* __restrict__ bias,     // [25]
        float* __restrict__ out_logits,
        float* __restrict__ out_act,
        float* __restrict__ out_coef) {
    const int b = blockIdx.x;
    __shared__ uint  vote_s[VOTE_B / 2];          // 44,800 B (fp16 pairs)
    __shared__ float coef_s[N_ROUTES * KCLS];
    __shared__ float act_s[8];

    const int tid = threadIdx.x, l = tid & 63, wv = tid >> 6;
    const int sub = l & 15, mg = l >> 4;
    const int m = wv + 8 * mg;
    const bool mv = (m < KCLS);
    const int mc = mv ? m : 24;                   // clamp for safe LDS reads

    {   // stage votes (coalesced uint4)
        const uint4* src = (const uint4*)(vote16 + (size_t)b * VOTE_B);
        uint4* dst = (uint4*)vote_s;
        for (int i = tid; i < VOTE_B / 8; i += 512) dst[i] = src[i];
    }
    if (tid < N_ROUTES) {
        float a = act[(size_t)b * N_ROUTES + tid];
        act_s[tid] = a;
        out_act[(size_t)b * N_ROUTES + tid] = a;
    }
    float g[8], be[8];
    *(float4*)(g)      = *(const float4*)(gamma + 8 * sub);
    *(float4*)(g + 4)  = *(const float4*)(gamma + 8 * sub + 4);
    *(float4*)(be)     = *(const float4*)(beta  + 8 * sub);
    *(float4*)(be + 4) = *(const float4*)(beta  + 8 * sub + 4);
    __syncthreads();

    const uint4* vs = (const uint4*)vote_s;       // idx: n*400 + m*16 + sub
    const float scale = 0.088388347648318447f;    // 1/sqrt(128)
    float pose[8];

    auto update = [&](bool first) {
        float r[8];
#pragma unroll
        for (int j = 0; j < 8; j++) r[j] = 0.f;
#pragma unroll
        for (int n = 0; n < N_ROUTES; n++) {
            float c = first ? (act_s[n] * 0.04f) : (coef_s[n * KCLS + mc] * act_s[n]);
            uint4 qv = vs[n * 400 + mc * 16 + sub];
            float2 f0 = h2f2(qv.x), f1 = h2f2(qv.y), f2 = h2f2(qv.z), f3 = h2f2(qv.w);
            r[0] += c * f0.x; r[1] += c * f0.y; r[2] += c * f1.x; r[3] += c * f1.y;
            r[4] += c * f2.x; r[5] += c * f2.y; r[6] += c * f3.x; r[7] += c * f3.y;
        }
        float S = 0.f, Q = 0.f;
#pragma unroll
        for (int j = 0; j < 8; j++) { S += r[j]; Q += r[j] * r[j]; }
#pragma unroll
        for (int o = 8; o; o >>= 1) {
            S += __shfl_xor(S, o);
            Q += __shfl_xor(Q, o);
        }
        float mean = S * 0.0078125f;
        float var  = Q * 0.0078125f - mean * mean;
        float rs   = rsqrtf(var + 1e-5f);
#pragma unroll
        for (int j = 0; j < 8; j++) pose[j] = (r[j] - mean) * rs * g[j] + be[j];
        __syncthreads();   // coef_s reads done before next agree overwrites
    };

    update(true);

    for (int it = 1; it < 3; it++) {
        // agreement: d[n] = <vote[n][m], pose[m]>
        float d[N_ROUTES];
#pragma unroll
        for (int n = 0; n < N_ROUTES; n++) {
            uint4 qv = vs[n * 400 + mc * 16 + sub];
            float2 f0 = h2f2(qv.x), f1 = h2f2(qv.y), f2 = h2f2(qv.z), f3 = h2f2(qv.w);
            d[n] = f0.x * pose[0] + f0.y * pose[1] + f1.x * pose[2] + f1.y * pose[3]
                 + f2.x * pose[4] + f2.y * pose[5] + f3.x * pose[6] + f3.y * pose[7];
        }
#pragma unroll
        for (int o = 8; o; o >>= 1)
#pragma unroll
            for (int n = 0; n < N_ROUTES; n++) d[n] += __shfl_xor(d[n], o);
        if (sub == 0 && mv) {
#pragma unroll
            for (int n = 0; n < N_ROUTES; n++) coef_s[n * KCLS + m] = d[n] * scale;
        }
        __syncthreads();
        // softmax over m per route (tiny, 7 threads)
        if (tid < N_ROUTES) {
            float mx = -1e30f;
            for (int mm = 0; mm < KCLS; mm++) mx = fmaxf(mx, coef_s[tid * KCLS + mm]);
            float s = 0.f;
            float e[KCLS];
            for (int mm = 0; mm < KCLS; mm++) { e[mm] = expf(coef_s[tid * KCLS + mm] - mx); s += e[mm]; }
            float inv = 1.0f / s;
            for (int mm = 0; mm < KCLS; mm++) coef_s[tid * KCLS + mm] = e[mm] * inv;
        }
        __syncthreads();
        update(false);
    }

    // logits
    float e[8];
    *(float4*)(e)     = *(const float4*)(emb + mc * MC_DIM + 8 * sub);
    *(float4*)(e + 4) = *(const float4*)(emb + mc * MC_DIM + 8 * sub + 4);
    float dd = 0.f;
#pragma unroll
    for (int j = 0; j < 8; j++) dd += pose[j] * e[j];
#pragma unroll
    for (int o = 8; o; o >>= 1) dd += __shfl_xor(dd, o);
    if (sub == 0 && mv) out_logits[(size_t)b * KCLS + m] = dd + bias[m];

    if (tid < N_ROUTES * KCLS)
        out_coef[(size_t)b * (N_ROUTES * KCLS) + tid] = coef_s[tid];
}

// ---------------- launch ----------------
extern "C" void kernel_launch(void* const* d_in, const int* in_sizes, int n_in,
                              void* d_out, int out_size, void* d_ws, size_t ws_size,
                              hipStream_t stream) {
    const float* pose  = (const float*)d_in[0];
    const float* act   = (const float*)d_in[1];
    const float* w     = (const float*)d_in[2];
    const float* gamma = (const float*)d_in[3];
    const float* beta  = (const float*)d_in[4];
    const float* emb   = (const float*)d_in[5];
    const float* bias  = (const float*)d_in[6];

    float* out        = (float*)d_out;
    float* out_logits = out;
    float* out_act    = out + BATCH * KCLS;
    float* out_coef   = out + BATCH * KCLS + BATCH * N_ROUTES;

    // workspace: wt fp16 | poseb fp16 | vote fp16 (chunked)
    const size_t wt_bytes    = (size_t)N_ROUTES * JDIM * PC_DIM * 2;
    const size_t poseb_bytes = (size_t)BATCH * ROW_IN * 2;
    ushort* wt    = (ushort*)d_ws;
    ushort* poseb = (ushort*)((char*)d_ws + wt_bytes);
    ushort* voteh = (ushort*)((char*)d_ws + wt_bytes + poseb_bytes);

    size_t rem = ws_size > wt_bytes + poseb_bytes ? ws_size - wt_bytes - poseb_bytes : 0;
    size_t cap = rem / ((size_t)VOTE_B * 2);
    int chunk;
    if (cap >= (size_t)BATCH)  chunk = BATCH;
    else if (cap >= 128)       chunk = (int)(cap & ~(size_t)127);
    else                       chunk = (int)(cap > 0 ? cap : 1);

    conv_w<<<dim3(JDIM / 32, PC_DIM / 32, N_ROUTES), 256, 0, stream>>>(w, wt);
    const int n8 = BATCH * ROW_IN / 8;
    conv_pose<<<(n8 + 255) / 256, 256, 0, stream>>>(pose, poseb, n8);

    for (int b0 = 0; b0 < BATCH; b0 += chunk) {
        int rows = BATCH - b0 < chunk ? BATCH - b0 : chunk;
        dim3 g1(JDIM / GBN, (rows + GBM - 1) / GBM, N_ROUTES);
        vote_gemm_mfma<<<g1, 256, 0, stream>>>(poseb + (size_t)b0 * ROW_IN, wt, voteh, rows);
        routing_kernel<<<rows, 512, 0, stream>>>(
            voteh,
            act + (size_t)b0 * N_ROUTES,
            gamma, beta, emb, bias,
            out_logits + (size_t)b0 * KCLS,
            out_act    + (size_t)b0 * N_ROUTES,
            out_coef   + (size_t)b0 * N_ROUTES * KCLS);
    }
}

// Round 6
// 395.406 us; speedup vs baseline: 5.0022x; 1.0163x over previous
//
#include <hip/hip_runtime.h>
#include <hip/hip_bf16.h>
#include <math.h>

// Problem constants
#define N_ROUTES 7
#define PC_DIM   512
#define MC_DIM   128
#define KCLS     25
#define BATCH    4096

#define ROW_IN   (N_ROUTES * PC_DIM)          // 3584 elems per batch row of pose
#define JDIM     (KCLS * MC_DIM)              // 3200 vote cols per route
#define VOTE_B   (N_ROUTES * JDIM)            // 22400 vote elems per batch elem

typedef __attribute__((ext_vector_type(8))) _Float16 half8;
typedef __attribute__((ext_vector_type(4))) float f32x4;

__device__ inline ushort f2h(float f) {
    _Float16 h = (_Float16)f;
    return __builtin_bit_cast(ushort, h);
}

__device__ inline float2 h2f2(uint u) {
    union { uint x; _Float16 h[2]; } c; c.x = u;
    return make_float2((float)c.h[0], (float)c.h[1]);
}

__device__ inline void load_lds16(const void* g, void* l) {
    __builtin_amdgcn_global_load_lds(
        (const __attribute__((address_space(1))) void*)g,
        (__attribute__((address_space(3))) void*)l, 16, 0, 0);
}

// ---------------- conversion kernels ----------------
__global__ __launch_bounds__(256) void conv_pose(const float* __restrict__ p,
                                                 ushort* __restrict__ pb, int n8) {
    int i = blockIdx.x * 256 + threadIdx.x;
    if (i >= n8) return;
    const float4* s = (const float4*)p + (size_t)i * 2;
    float4 a = s[0], b = s[1];
    ushort t[8];
    t[0]=f2h(a.x); t[1]=f2h(a.y); t[2]=f2h(a.z); t[3]=f2h(a.w);
    t[4]=f2h(b.x); t[5]=f2h(b.y); t[6]=f2h(b.z); t[7]=f2h(b.w);
    *(uint4*)(pb + (size_t)i * 8) = *(uint4*)t;
}

// w fp32 [7][512][3200] -> wt fp16 [7][3200][512] (transposed per route)
__global__ __launch_bounds__(256) void conv_w(const float* __restrict__ w,
                                              ushort* __restrict__ wt) {
    __shared__ float t[32][33];
    const int j0 = blockIdx.x * 32, d0 = blockIdx.y * 32, r = blockIdx.z;
    const int c = threadIdx.x & 31, rr = threadIdx.x >> 5;
    const float* wp = w + (size_t)r * PC_DIM * JDIM;
#pragma unroll
    for (int i = 0; i < 4; i++)
        t[rr + i * 8][c] = wp[(size_t)(d0 + rr + i * 8) * JDIM + j0 + c];
    __syncthreads();
    ushort* op = wt + (size_t)r * JDIM * PC_DIM;
#pragma unroll
    for (int i = 0; i < 4; i++)
        op[(size_t)(j0 + rr + i * 8) * PC_DIM + d0 + c] = f2h(t[c][rr + i * 8]);
}

// ---------------- Kernel 1: MFMA vote GEMM (fp16 in, fp16 out) ----------------
// 128x128 tile, BK=64 (8 K-iters), 4 waves (2x2), each wave 4x4 of 16x16x32 MFMA.
// 1D grid, row-slab-outer ordering for A-tile L2 locality.
#define GBM 128
#define GBN 128
#define GBK 64

__global__ __launch_bounds__(256) void vote_gemm_mfma(
        const ushort* __restrict__ poseb,  // [rows][3584] fp16
        const ushort* __restrict__ wt,     // [7][3200][512] fp16
        ushort* __restrict__ vote,         // [rows][7][3200] fp16
        int rows) {
    // id -> (rowTile outer, (route, jTile) inner): 175 blocks share one A slab
    const int id = blockIdx.x;
    const int rowTile = id / (N_ROUTES * 25);
    const int rem = id - rowTile * (N_ROUTES * 25);
    const int route = rem / 25;
    const int jTile = rem - route * 25;
    const int b0 = rowTile * GBM;
    const int j0 = jTile * GBN;

    // As/Bs: 128 rows x 8 chunks of 8 fp16 (16 KB each). Epilogue overlays 17408 B.
    __shared__ __align__(16) char smem[32768];
    ushort* As = (ushort*)smem;
    ushort* Bs = As + GBM * GBK;

    const int tid = threadIdx.x;
    const int l = tid & 63, w = tid >> 6;
    const int wm = w >> 1, wn = w & 1;

    f32x4 acc[4][4] = {};

    const ushort* Aptr = poseb + (size_t)route * PC_DIM;
    const ushort* Bptr = wt + (size_t)route * JDIM * PC_DIM;

    const int q4 = l >> 4;           // quad id 0..3 -> k-offset within 32-k sub-block
    const int swz = l & 7;           // row-based swizzle (row&7 == l&7 for 16-aligned bases)

    for (int k0 = 0; k0 < PC_DIM; k0 += GBK) {
        // stage: 1024 slots x 16B per matrix; slot (row, c) holds global chunk c ^ (row&7)
        int f = tid;
#pragma unroll
        for (int i = 0; i < 4; i++, f += 256) {
            const int row = f >> 3;
            const int c = f & 7;
            const int qg = c ^ (row & 7);
            int ga = b0 + row; if (ga >= rows) ga = rows - 1;
            load_lds16(Aptr + (size_t)ga * ROW_IN + k0 + qg * 8, As + (size_t)f * 8);
            load_lds16(Bptr + (size_t)(j0 + row) * PC_DIM + k0 + qg * 8, Bs + (size_t)f * 8);
        }
        __syncthreads();

#pragma unroll
        for (int s = 0; s < 2; s++) {      // two 32-k sub-blocks
            half8 af[4], bfg[4];
#pragma unroll
            for (int t = 0; t < 4; t++) {
                const int rowA = wm * 64 + t * 16 + (l & 15);
                const int rowB = wn * 64 + t * 16 + (l & 15);
                const int c = (s * 4 + q4) ^ swz;
                af[t]  = *(const half8*)(As + (size_t)(rowA * 8 + c) * 8);
                bfg[t] = *(const half8*)(Bs + (size_t)(rowB * 8 + c) * 8);
            }
#pragma unroll
            for (int mt = 0; mt < 4; mt++)
#pragma unroll
                for (int nt = 0; nt < 4; nt++)
                    acc[mt][nt] = __builtin_amdgcn_mfma_f32_16x16x32_f16(
                        af[mt], bfg[nt], acc[mt][nt], 0, 0, 0);
        }
        __syncthreads();
    }

    // Epilogue: per-wave LDS transpose, convert to fp16, 32B/lane stores.
    float* ep = (float*)smem + w * 16 * 68;
    const int erow = l >> 2;
    const int ec0  = (l & 3) * 16;
#pragma unroll
    for (int mt = 0; mt < 4; mt++) {
#pragma unroll
        for (int nt = 0; nt < 4; nt++)
#pragma unroll
            for (int i = 0; i < 4; i++)
                ep[((l >> 4) * 4 + i) * 68 + nt * 16 + (l & 15)] = acc[mt][nt][i];
        __syncthreads();
        const int grow = b0 + wm * 64 + mt * 16 + erow;
        if (grow < rows) {
            ushort t16[16];
#pragma unroll
            for (int t8 = 0; t8 < 4; t8++) {
                float4 v = *(float4*)&ep[erow * 68 + ec0 + t8 * 4];
                t16[t8*4+0]=f2h(v.x); t16[t8*4+1]=f2h(v.y);
                t16[t8*4+2]=f2h(v.z); t16[t8*4+3]=f2h(v.w);
            }
            ushort* dst = vote + (size_t)grow * VOTE_B + route * JDIM + j0 + wn * 64 + ec0;
            ((uint4*)dst)[0] = ((uint4*)t16)[0];
            ((uint4*)dst)[1] = ((uint4*)t16)[1];
        }
        __syncthreads();
    }
}

// ---------------- Kernel 2: fused routing (register-resident votes) ----------------
// Block = one batch elem, 512 threads (8 waves). Lane decomposition:
//   sub = l&15 -> v-dims [8*sub, 8*sub+8);  mg = l>>4;  m = wv + 8*mg.
// Each thread holds vote[n][m][8 dims] for all 7 routes in 7 uint4 registers.
// Reductions: 4-step shfl over 16 lanes. LDS only for coef/act (~1 KB).
__global__ __launch_bounds__(512) void routing_kernel(
        const ushort* __restrict__ vote16,  // [chunk][7][25][128] fp16
        const float* __restrict__ act,      // (pre-offset)
        const float* __restrict__ gamma,
        const float* __restrict__ beta,
        const float* __restrict__ emb,      // [25,128]
        const float* __restrict__ bias,     // [25]
        float* __restrict__ out_logits,
        float* __restrict__ out_act,
        float* __restrict__ out_coef) {
    const int b = blockIdx.x;
    __shared__ float coef_s[N_ROUTES * KCLS];
    __shared__ float act_s[8];

    const int tid = threadIdx.x, l = tid & 63, wv = tid >> 6;
    const int sub = l & 15, mg = l >> 4;
    const int m = wv + 8 * mg;
    const bool mv = (m < KCLS);
    const int mc = mv ? m : 24;                   // clamp for safe reads

    if (tid < N_ROUTES) {
        float a = act[(size_t)b * N_ROUTES + tid];
        act_s[tid] = a;
        out_act[(size_t)b * N_ROUTES + tid] = a;
    }

    // votes into registers: 7 independent coalesced 16B loads
    uint4 v[N_ROUTES];
    const uint4* vb = (const uint4*)(vote16 + (size_t)b * VOTE_B);  // idx n*400 + m*16 + sub
#pragma unroll
    for (int n = 0; n < N_ROUTES; n++)
        v[n] = vb[n * 400 + mc * 16 + sub];

    float g[8], be[8];
    *(float4*)(g)      = *(const float4*)(gamma + 8 * sub);
    *(float4*)(g + 4)  = *(const float4*)(gamma + 8 * sub + 4);
    *(float4*)(be)     = *(const float4*)(beta  + 8 * sub);
    *(float4*)(be + 4) = *(const float4*)(beta  + 8 * sub + 4);
    __syncthreads();   // act_s ready

    const float scale = 0.088388347648318447f;    // 1/sqrt(128)
    float pose[8];

    auto update = [&](bool first) {
        float r[8];
#pragma unroll
        for (int j = 0; j < 8; j++) r[j] = 0.f;
#pragma unroll
        for (int n = 0; n < N_ROUTES; n++) {
            float c = first ? (act_s[n] * 0.04f) : (coef_s[n * KCLS + mc] * act_s[n]);
            float2 f0 = h2f2(v[n].x), f1 = h2f2(v[n].y), f2 = h2f2(v[n].z), f3 = h2f2(v[n].w);
            r[0] += c * f0.x; r[1] += c * f0.y; r[2] += c * f1.x; r[3] += c * f1.y;
            r[4] += c * f2.x; r[5] += c * f2.y; r[6] += c * f3.x; r[7] += c * f3.y;
        }
        float S = 0.f, Q = 0.f;
#pragma unroll
        for (int j = 0; j < 8; j++) { S += r[j]; Q += r[j] * r[j]; }
#pragma unroll
        for (int o = 8; o; o >>= 1) {
            S += __shfl_xor(S, o);
            Q += __shfl_xor(Q, o);
        }
        float mean = S * 0.0078125f;
        float var  = Q * 0.0078125f - mean * mean;
        float rs   = rsqrtf(var + 1e-5f);
#pragma unroll
        for (int j = 0; j < 8; j++) pose[j] = (r[j] - mean) * rs * g[j] + be[j];
        __syncthreads();   // coef_s reads done before next agree overwrites
    };

    update(true);

    for (int it = 1; it < 3; it++) {
        // agreement: d[n] = <vote[n][m], pose[m]>
        float d[N_ROUTES];
#pragma unroll
        for (int n = 0; n < N_ROUTES; n++) {
            float2 f0 = h2f2(v[n].x), f1 = h2f2(v[n].y), f2 = h2f2(v[n].z), f3 = h2f2(v[n].w);
            d[n] = f0.x * pose[0] + f0.y * pose[1] + f1.x * pose[2] + f1.y * pose[3]
                 + f2.x * pose[4] + f2.y * pose[5] + f3.x * pose[6] + f3.y * pose[7];
        }
#pragma unroll
        for (int o = 8; o; o >>= 1)
#pragma unroll
            for (int n = 0; n < N_ROUTES; n++) d[n] += __shfl_xor(d[n], o);
        if (sub == 0 && mv) {
#pragma unroll
            for (int n = 0; n < N_ROUTES; n++) coef_s[n * KCLS + m] = d[n] * scale;
        }
        __syncthreads();
        // softmax over m per route (tiny, 7 threads)
        if (tid < N_ROUTES) {
            float mx = -1e30f;
            for (int mm = 0; mm < KCLS; mm++) mx = fmaxf(mx, coef_s[tid * KCLS + mm]);
            float s = 0.f;
            float e[KCLS];
            for (int mm = 0; mm < KCLS; mm++) { e[mm] = expf(coef_s[tid * KCLS + mm] - mx); s += e[mm]; }
            float inv = 1.0f / s;
            for (int mm = 0; mm < KCLS; mm++) coef_s[tid * KCLS + mm] = e[mm] * inv;
        }
        __syncthreads();
        update(false);
    }

    // logits
    float e[8];
    *(float4*)(e)     = *(const float4*)(emb + mc * MC_DIM + 8 * sub);
    *(float4*)(e + 4) = *(const float4*)(emb + mc * MC_DIM + 8 * sub + 4);
    float dd = 0.f;
#pragma unroll
    for (int j = 0; j < 8; j++) dd += pose[j] * e[j];
#pragma unroll
    for (int o = 8; o; o >>= 1) dd += __shfl_xor(dd, o);
    if (sub == 0 && mv) out_logits[(size_t)b * KCLS + m] = dd + bias[m];

    if (tid < N_ROUTES * KCLS)
        out_coef[(size_t)b * (N_ROUTES * KCLS) + tid] = coef_s[tid];
}

// ---------------- launch ----------------
extern "C" void kernel_launch(void* const* d_in, const int* in_sizes, int n_in,
                              void* d_out, int out_size, void* d_ws, size_t ws_size,
                              hipStream_t stream) {
    const float* pose  = (const float*)d_in[0];
    const float* act   = (const float*)d_in[1];
    const float* w     = (const float*)d_in[2];
    const float* gamma = (const float*)d_in[3];
    const float* beta  = (const float*)d_in[4];
    const float* emb   = (const float*)d_in[5];
    const float* bias  = (const float*)d_in[6];

    float* out        = (float*)d_out;
    float* out_logits = out;
    float* out_act    = out + BATCH * KCLS;
    float* out_coef   = out + BATCH * KCLS + BATCH * N_ROUTES;

    // workspace: wt fp16 | poseb fp16 | vote fp16 (chunked)
    const size_t wt_bytes    = (size_t)N_ROUTES * JDIM * PC_DIM * 2;
    const size_t poseb_bytes = (size_t)BATCH * ROW_IN * 2;
    ushort* wt    = (ushort*)d_ws;
    ushort* poseb = (ushort*)((char*)d_ws + wt_bytes);
    ushort* voteh = (ushort*)((char*)d_ws + wt_bytes + poseb_bytes);

    size_t rem = ws_size > wt_bytes + poseb_bytes ? ws_size - wt_bytes - poseb_bytes : 0;
    size_t cap = rem / ((size_t)VOTE_B * 2);
    int chunk;
    if (cap >= (size_t)BATCH)  chunk = BATCH;
    else if (cap >= 128)       chunk = (int)(cap & ~(size_t)127);
    else                       chunk = (int)(cap > 0 ? cap : 1);

    conv_w<<<dim3(JDIM / 32, PC_DIM / 32, N_ROUTES), 256, 0, stream>>>(w, wt);
    const int n8 = BATCH * ROW_IN / 8;
    conv_pose<<<(n8 + 255) / 256, 256, 0, stream>>>(pose, poseb, n8);

    for (int b0 = 0; b0 < BATCH; b0 += chunk) {
        int rows = BATCH - b0 < chunk ? BATCH - b0 : chunk;
        int nRowTiles = (rows + GBM - 1) / GBM;
        vote_gemm_mfma<<<nRowTiles * N_ROUTES * 25, 256, 0, stream>>>(
            poseb + (size_t)b0 * ROW_IN, wt, voteh, rows);
        routing_kernel<<<rows, 512, 0, stream>>>(
            voteh,
            act + (size_t)b0 * N_ROUTES,
            gamma, beta, emb, bias,
            out_logits + (size_t)b0 * KCLS,
            out_act    + (size_t)b0 * N_ROUTES,
            out_coef   + (size_t)b0 * N_ROUTES * KCLS);
    }
}

// Round 7
// 376.102 us; speedup vs baseline: 5.2590x; 1.0513x over previous
//
#include <hip/hip_runtime.h>
#include <hip/hip_bf16.h>
#include <math.h>

// Problem constants
#define N_ROUTES 7
#define PC_DIM   512
#define MC_DIM   128
#define KCLS     25
#define BATCH    4096

#define ROW_IN   (N_ROUTES * PC_DIM)          // 3584 elems per batch row of pose
#define JDIM     (KCLS * MC_DIM)              // 3200 vote cols per route
#define VOTE_B   (N_ROUTES * JDIM)            // 22400 vote elems per batch elem

typedef __attribute__((ext_vector_type(8))) _Float16 half8;
typedef __attribute__((ext_vector_type(4))) float f32x4;

__device__ inline ushort f2h(float f) {
    _Float16 h = (_Float16)f;
    return __builtin_bit_cast(ushort, h);
}

__device__ inline float2 h2f2(uint u) {
    union { uint x; _Float16 h[2]; } c; c.x = u;
    return make_float2((float)c.h[0], (float)c.h[1]);
}

__device__ inline void load_lds16(const void* g, void* l) {
    __builtin_amdgcn_global_load_lds(
        (const __attribute__((address_space(1))) void*)g,
        (__attribute__((address_space(3))) void*)l, 16, 0, 0);
}

// ---------------- conversion kernels ----------------
__global__ __launch_bounds__(256) void conv_pose(const float* __restrict__ p,
                                                 ushort* __restrict__ pb, int n8) {
    int i = blockIdx.x * 256 + threadIdx.x;
    if (i >= n8) return;
    const float4* s = (const float4*)p + (size_t)i * 2;
    float4 a = s[0], b = s[1];
    ushort t[8];
    t[0]=f2h(a.x); t[1]=f2h(a.y); t[2]=f2h(a.z); t[3]=f2h(a.w);
    t[4]=f2h(b.x); t[5]=f2h(b.y); t[6]=f2h(b.z); t[7]=f2h(b.w);
    *(uint4*)(pb + (size_t)i * 8) = *(uint4*)t;
}

// w fp32 [7][512][3200] -> wt fp16 [7][3200][512] (transposed per route)
__global__ __launch_bounds__(256) void conv_w(const float* __restrict__ w,
                                              ushort* __restrict__ wt) {
    __shared__ float t[32][33];
    const int j0 = blockIdx.x * 32, d0 = blockIdx.y * 32, r = blockIdx.z;
    const int c = threadIdx.x & 31, rr = threadIdx.x >> 5;
    const float* wp = w + (size_t)r * PC_DIM * JDIM;
#pragma unroll
    for (int i = 0; i < 4; i++)
        t[rr + i * 8][c] = wp[(size_t)(d0 + rr + i * 8) * JDIM + j0 + c];
    __syncthreads();
    ushort* op = wt + (size_t)r * JDIM * PC_DIM;
#pragma unroll
    for (int i = 0; i < 4; i++)
        op[(size_t)(j0 + rr + i * 8) * PC_DIM + d0 + c] = f2h(t[c][rr + i * 8]);
}

// ---------------- Kernel 1: MFMA vote GEMM (fp16 in, fp16 out) ----------------
// 128x128 tile, BK=64 (8 K-iters), 4 waves (2x2), each wave 4x4 of 16x16x32 MFMA.
// XCD-aware swizzle: id&7 = XCD (round-robin dispatch heuristic); each XCD walks
// 28 (route,rowTile) pairs route-major, 25 jTiles inner -> per-XCD L2 working set
// = one route's B (3.27 MB) + one A slab (131 KB).
#define GBM 128
#define GBN 128
#define GBK 64

__global__ __launch_bounds__(256) void vote_gemm_mfma(
        const ushort* __restrict__ poseb,  // [rows][3584] fp16
        const ushort* __restrict__ wt,     // [7][3200][512] fp16
        ushort* __restrict__ vote,         // [rows][7][3200] fp16
        int rows) {
    int route, rowTile, jTile;
    if (gridDim.x == 5600) {               // full batch: 32 rowTiles x 7 routes x 25 jTiles
        const int x = blockIdx.x & 7;      // XCD id (heuristic, perf-only)
        const int g = blockIdx.x >> 3;     // 0..699 per XCD
        const int q = g / 25;              // 0..27
        jTile = g - q * 25;
        const int p = x * 28 + q;          // 0..223 = route*32 + rowTile
        route = p >> 5;
        rowTile = p & 31;
    } else {                               // fallback: route-outer, jTile-inner
        const int nrt = gridDim.x / (N_ROUTES * 25);
        route = blockIdx.x / (nrt * 25);
        const int r2 = blockIdx.x - route * nrt * 25;
        rowTile = r2 / 25;
        jTile = r2 - rowTile * 25;
    }
    const int b0 = rowTile * GBM;
    const int j0 = jTile * GBN;

    // As/Bs: 128 rows x 8 chunks of 8 fp16 (16 KB each). Epilogue overlays 17408 B.
    __shared__ __align__(16) char smem[32768];
    ushort* As = (ushort*)smem;
    ushort* Bs = As + GBM * GBK;

    const int tid = threadIdx.x;
    const int l = tid & 63, w = tid >> 6;
    const int wm = w >> 1, wn = w & 1;

    f32x4 acc[4][4] = {};

    const ushort* Aptr = poseb + (size_t)route * PC_DIM;
    const ushort* Bptr = wt + (size_t)route * JDIM * PC_DIM;

    const int q4 = l >> 4;           // quad id 0..3 -> k-offset within 32-k sub-block
    const int swz = l & 7;           // row-based swizzle (row&7 == l&7 for 16-aligned bases)

    for (int k0 = 0; k0 < PC_DIM; k0 += GBK) {
        // stage: 1024 slots x 16B per matrix; slot (row, c) holds global chunk c ^ (row&7)
        int f = tid;
#pragma unroll
        for (int i = 0; i < 4; i++, f += 256) {
            const int row = f >> 3;
            const int c = f & 7;
            const int qg = c ^ (row & 7);
            int ga = b0 + row; if (ga >= rows) ga = rows - 1;
            load_lds16(Aptr + (size_t)ga * ROW_IN + k0 + qg * 8, As + (size_t)f * 8);
            load_lds16(Bptr + (size_t)(j0 + row) * PC_DIM + k0 + qg * 8, Bs + (size_t)f * 8);
        }
        __syncthreads();

#pragma unroll
        for (int s = 0; s < 2; s++) {      // two 32-k sub-blocks
            half8 af[4], bfg[4];
#pragma unroll
            for (int t = 0; t < 4; t++) {
                const int rowA = wm * 64 + t * 16 + (l & 15);
                const int rowB = wn * 64 + t * 16 + (l & 15);
                const int c = (s * 4 + q4) ^ swz;
                af[t]  = *(const half8*)(As + (size_t)(rowA * 8 + c) * 8);
                bfg[t] = *(const half8*)(Bs + (size_t)(rowB * 8 + c) * 8);
            }
#pragma unroll
            for (int mt = 0; mt < 4; mt++)
#pragma unroll
                for (int nt = 0; nt < 4; nt++)
                    acc[mt][nt] = __builtin_amdgcn_mfma_f32_16x16x32_f16(
                        af[mt], bfg[nt], acc[mt][nt], 0, 0, 0);
        }
        __syncthreads();
    }

    // Epilogue: per-wave LDS transpose, convert to fp16, 32B/lane stores.
    float* ep = (float*)smem + w * 16 * 68;
    const int erow = l >> 2;
    const int ec0  = (l & 3) * 16;
#pragma unroll
    for (int mt = 0; mt < 4; mt++) {
#pragma unroll
        for (int nt = 0; nt < 4; nt++)
#pragma unroll
            for (int i = 0; i < 4; i++)
                ep[((l >> 4) * 4 + i) * 68 + nt * 16 + (l & 15)] = acc[mt][nt][i];
        __syncthreads();
        const int grow = b0 + wm * 64 + mt * 16 + erow;
        if (grow < rows) {
            ushort t16[16];
#pragma unroll
            for (int t8 = 0; t8 < 4; t8++) {
                float4 v = *(float4*)&ep[erow * 68 + ec0 + t8 * 4];
                t16[t8*4+0]=f2h(v.x); t16[t8*4+1]=f2h(v.y);
                t16[t8*4+2]=f2h(v.z); t16[t8*4+3]=f2h(v.w);
            }
            ushort* dst = vote + (size_t)grow * VOTE_B + route * JDIM + j0 + wn * 64 + ec0;
            ((uint4*)dst)[0] = ((uint4*)t16)[0];
            ((uint4*)dst)[1] = ((uint4*)t16)[1];
        }
        __syncthreads();
    }
}

// ---------------- Kernel 2: fused routing (register-resident votes) ----------------
// Block = one batch elem, 512 threads (8 waves). Lane decomposition:
//   sub = l&15 -> v-dims [8*sub, 8*sub+8);  mg = l>>4;  m = wv + 8*mg.
// Reductions: 4-step shfl over 16 lanes. Parallel softmax: 7 x 32-lane groups.
__global__ __launch_bounds__(512) void routing_kernel(
        const ushort* __restrict__ vote16,  // [chunk][7][25][128] fp16
        const float* __restrict__ act,      // (pre-offset)
        const float* __restrict__ gamma,
        const float* __restrict__ beta,
        const float* __restrict__ emb,      // [25,128]
        const float* __restrict__ bias,     // [25]
        float* __restrict__ out_logits,
        float* __restrict__ out_act,
        float* __restrict__ out_coef) {
    const int b = blockIdx.x;
    __shared__ float coef_s[N_ROUTES * KCLS];
    __shared__ float act_s[8];

    const int tid = threadIdx.x, l = tid & 63, wv = tid >> 6;
    const int sub = l & 15, mg = l >> 4;
    const int m = wv + 8 * mg;
    const bool mv = (m < KCLS);

    if (tid < N_ROUTES) {
        float a = act[(size_t)b * N_ROUTES + tid];
        act_s[tid] = a;
        out_act[(size_t)b * N_ROUTES + tid] = a;
    }

    // votes into registers: 7 coalesced 16B loads; invalid m-groups skip (exec-masked)
    uint4 v[N_ROUTES] = {};
    if (mv) {
        const uint4* vb = (const uint4*)(vote16 + (size_t)b * VOTE_B);  // n*400 + m*16 + sub
#pragma unroll
        for (int n = 0; n < N_ROUTES; n++)
            v[n] = vb[n * 400 + m * 16 + sub];
    }
    const int mc = mv ? m : 24;

    float g[8], be[8];
    *(float4*)(g)      = *(const float4*)(gamma + 8 * sub);
    *(float4*)(g + 4)  = *(const float4*)(gamma + 8 * sub + 4);
    *(float4*)(be)     = *(const float4*)(beta  + 8 * sub);
    *(float4*)(be + 4) = *(const float4*)(beta  + 8 * sub + 4);
    __syncthreads();   // act_s ready

    const float scale = 0.088388347648318447f;    // 1/sqrt(128)
    float pose[8];

    auto update = [&](bool first) {
        float r[8];
#pragma unroll
        for (int j = 0; j < 8; j++) r[j] = 0.f;
#pragma unroll
        for (int n = 0; n < N_ROUTES; n++) {
            float c = first ? (act_s[n] * 0.04f) : (coef_s[n * KCLS + mc] * act_s[n]);
            float2 f0 = h2f2(v[n].x), f1 = h2f2(v[n].y), f2 = h2f2(v[n].z), f3 = h2f2(v[n].w);
            r[0] += c * f0.x; r[1] += c * f0.y; r[2] += c * f1.x; r[3] += c * f1.y;
            r[4] += c * f2.x; r[5] += c * f2.y; r[6] += c * f3.x; r[7] += c * f3.y;
        }
        float S = 0.f, Q = 0.f;
#pragma unroll
        for (int j = 0; j < 8; j++) { S += r[j]; Q += r[j] * r[j]; }
#pragma unroll
        for (int o = 8; o; o >>= 1) {
            S += __shfl_xor(S, o);
            Q += __shfl_xor(Q, o);
        }
        float mean = S * 0.0078125f;
        float var  = Q * 0.0078125f - mean * mean;
        float rs   = rsqrtf(var + 1e-5f);
#pragma unroll
        for (int j = 0; j < 8; j++) pose[j] = (r[j] - mean) * rs * g[j] + be[j];
        __syncthreads();   // coef_s reads done before next agree overwrites
    };

    update(true);

    const int sgrp = tid >> 5, slane = tid & 31;   // 16 x 32-lane groups for softmax

    for (int it = 1; it < 3; it++) {
        // agreement: d[n] = <vote[n][m], pose[m]>
        float d[N_ROUTES];
#pragma unroll
        for (int n = 0; n < N_ROUTES; n++) {
            float2 f0 = h2f2(v[n].x), f1 = h2f2(v[n].y), f2 = h2f2(v[n].z), f3 = h2f2(v[n].w);
            d[n] = f0.x * pose[0] + f0.y * pose[1] + f1.x * pose[2] + f1.y * pose[3]
                 + f2.x * pose[4] + f2.y * pose[5] + f3.x * pose[6] + f3.y * pose[7];
        }
#pragma unroll
        for (int o = 8; o; o >>= 1)
#pragma unroll
            for (int n = 0; n < N_ROUTES; n++) d[n] += __shfl_xor(d[n], o);
        if (sub == 0 && mv) {
#pragma unroll
            for (int n = 0; n < N_ROUTES; n++) coef_s[n * KCLS + m] = d[n] * scale;
        }
        __syncthreads();
        // parallel softmax: group sgrp = route, lane slane = m
        if (sgrp < N_ROUTES) {
            float c = (slane < KCLS) ? coef_s[sgrp * KCLS + slane] : -1e30f;
            float mx = c;
#pragma unroll
            for (int o = 16; o; o >>= 1) mx = fmaxf(mx, __shfl_xor(mx, o, 32));
            float e = (slane < KCLS) ? expf(c - mx) : 0.f;
            float s = e;
#pragma unroll
            for (int o = 16; o; o >>= 1) s += __shfl_xor(s, o, 32);
            if (slane < KCLS) coef_s[sgrp * KCLS + slane] = e / s;
        }
        __syncthreads();
        update(false);
    }

    // logits
    float e[8];
    *(float4*)(e)     = *(const float4*)(emb + mc * MC_DIM + 8 * sub);
    *(float4*)(e + 4) = *(const float4*)(emb + mc * MC_DIM + 8 * sub + 4);
    float dd = 0.f;
#pragma unroll
    for (int j = 0; j < 8; j++) dd += pose[j] * e[j];
#pragma unroll
    for (int o = 8; o; o >>= 1) dd += __shfl_xor(dd, o);
    if (sub == 0 && mv) out_logits[(size_t)b * KCLS + m] = dd + bias[m];

    if (tid < N_ROUTES * KCLS)
        out_coef[(size_t)b * (N_ROUTES * KCLS) + tid] = coef_s[tid];
}

// ---------------- launch ----------------
extern "C" void kernel_launch(void* const* d_in, const int* in_sizes, int n_in,
                              void* d_out, int out_size, void* d_ws, size_t ws_size,
                              hipStream_t stream) {
    const float* pose  = (const float*)d_in[0];
    const float* act   = (const float*)d_in[1];
    const float* w     = (const float*)d_in[2];
    const float* gamma = (const float*)d_in[3];
    const float* beta  = (const float*)d_in[4];
    const float* emb   = (const float*)d_in[5];
    const float* bias  = (const float*)d_in[6];

    float* out        = (float*)d_out;
    float* out_logits = out;
    float* out_act    = out + BATCH * KCLS;
    float* out_coef   = out + BATCH * KCLS + BATCH * N_ROUTES;

    // workspace: wt fp16 | poseb fp16 | vote fp16 (chunked)
    const size_t wt_bytes    = (size_t)N_ROUTES * JDIM * PC_DIM * 2;
    const size_t poseb_bytes = (size_t)BATCH * ROW_IN * 2;
    ushort* wt    = (ushort*)d_ws;
    ushort* poseb = (ushort*)((char*)d_ws + wt_bytes);
    ushort* voteh = (ushort*)((char*)d_ws + wt_bytes + poseb_bytes);

    size_t rem = ws_size > wt_bytes + poseb_bytes ? ws_size - wt_bytes - poseb_bytes : 0;
    size_t cap = rem / ((size_t)VOTE_B * 2);
    int chunk;
    if (cap >= (size_t)BATCH)  chunk = BATCH;
    else if (cap >= 128)       chunk = (int)(cap & ~(size_t)127);
    else                       chunk = (int)(cap > 0 ? cap : 1);

    conv_w<<<dim3(JDIM / 32, PC_DIM / 32, N_ROUTES), 256, 0, stream>>>(w, wt);
    const int n8 = BATCH * ROW_IN / 8;
    conv_pose<<<(n8 + 255) / 256, 256, 0, stream>>>(pose, poseb, n8);

    for (int b0 = 0; b0 < BATCH; b0 += chunk) {
        int rows = BATCH - b0 < chunk ? BATCH - b0 : chunk;
        int nRowTiles = (rows + GBM - 1) / GBM;
        vote_gemm_mfma<<<nRowTiles * N_ROUTES * 25, 256, 0, stream>>>(
            poseb + (size_t)b0 * ROW_IN, wt, voteh, rows);
        routing_kernel<<<rows, 512, 0, stream>>>(
            voteh,
            act + (size_t)b0 * N_ROUTES,
            gamma, beta, emb, bias,
            out_logits + (size_t)b0 * KCLS,
            out_act    + (size_t)b0 * N_ROUTES,
            out_coef   + (size_t)b0 * N_ROUTES * KCLS);
    }
}

// Round 8
// 348.679 us; speedup vs baseline: 5.6726x; 1.0786x over previous
//
#include <hip/hip_runtime.h>
#include <hip/hip_bf16.h>
#include <math.h>

// Problem constants
#define N_ROUTES 7
#define PC_DIM   512
#define MC_DIM   128
#define KCLS     25
#define BATCH    4096

#define ROW_IN   (N_ROUTES * PC_DIM)          // 3584 elems per batch row of pose
#define JDIM     (KCLS * MC_DIM)              // 3200 vote cols per route
#define VOTE_B   (N_ROUTES * JDIM)            // 22400 vote elems per batch elem

typedef __attribute__((ext_vector_type(8))) _Float16 half8;
typedef __attribute__((ext_vector_type(4))) float f32x4;

__device__ inline ushort f2h(float f) {
    _Float16 h = (_Float16)f;
    return __builtin_bit_cast(ushort, h);
}

__device__ inline float2 h2f2(uint u) {
    union { uint x; _Float16 h[2]; } c; c.x = u;
    return make_float2((float)c.h[0], (float)c.h[1]);
}

__device__ inline void load_lds16(const void* g, void* l) {
    __builtin_amdgcn_global_load_lds(
        (const __attribute__((address_space(1))) void*)g,
        (__attribute__((address_space(3))) void*)l, 16, 0, 0);
}

// ---------------- conversion kernels ----------------
__global__ __launch_bounds__(256) void conv_pose(const float* __restrict__ p,
                                                 ushort* __restrict__ pb, int n8) {
    int i = blockIdx.x * 256 + threadIdx.x;
    if (i >= n8) return;
    const float4* s = (const float4*)p + (size_t)i * 2;
    float4 a = s[0], b = s[1];
    ushort t[8];
    t[0]=f2h(a.x); t[1]=f2h(a.y); t[2]=f2h(a.z); t[3]=f2h(a.w);
    t[4]=f2h(b.x); t[5]=f2h(b.y); t[6]=f2h(b.z); t[7]=f2h(b.w);
    *(uint4*)(pb + (size_t)i * 8) = *(uint4*)t;
}

// w fp32 [7][512][3200] -> wt fp16 [7][3200][512] (transposed per route)
__global__ __launch_bounds__(256) void conv_w(const float* __restrict__ w,
                                              ushort* __restrict__ wt) {
    __shared__ float t[32][33];
    const int j0 = blockIdx.x * 32, d0 = blockIdx.y * 32, r = blockIdx.z;
    const int c = threadIdx.x & 31, rr = threadIdx.x >> 5;
    const float* wp = w + (size_t)r * PC_DIM * JDIM;
#pragma unroll
    for (int i = 0; i < 4; i++)
        t[rr + i * 8][c] = wp[(size_t)(d0 + rr + i * 8) * JDIM + j0 + c];
    __syncthreads();
    ushort* op = wt + (size_t)r * JDIM * PC_DIM;
#pragma unroll
    for (int i = 0; i < 4; i++)
        op[(size_t)(j0 + rr + i * 8) * PC_DIM + d0 + c] = f2h(t[c][rr + i * 8]);
}

// ---------------- Kernel 1: MFMA vote GEMM (fp16 in, fp16 out) ----------------
// 128x128 tile, BK=64 (8 K-iters), 4 waves (2x2), each wave 4x4 of 16x16x32 MFMA.
// XCD-aware swizzle (id&7 = XCD): per-XCD working set = ~1 route's B (3.27 MB, L2)
// + A slabs. Verified r7: FETCH 476 -> 162 MB, dur 192 -> 151 us.
#define GBM 128
#define GBN 128
#define GBK 64

__global__ __launch_bounds__(256) void vote_gemm_mfma(
        const ushort* __restrict__ poseb,  // [rows][3584] fp16
        const ushort* __restrict__ wt,     // [7][3200][512] fp16
        ushort* __restrict__ vote,         // [rows][7][3200] fp16
        int rows) {
    int route, rowTile, jTile;
    if (gridDim.x == 5600) {               // full batch: 32 rowTiles x 7 routes x 25 jTiles
        const int x = blockIdx.x & 7;      // XCD id (heuristic, perf-only)
        const int g = blockIdx.x >> 3;     // 0..699 per XCD
        const int q = g / 25;              // 0..27
        jTile = g - q * 25;
        const int p = x * 28 + q;          // 0..223 = route*32 + rowTile
        route = p >> 5;
        rowTile = p & 31;
    } else {                               // fallback: route-outer, jTile-inner
        const int nrt = gridDim.x / (N_ROUTES * 25);
        route = blockIdx.x / (nrt * 25);
        const int r2 = blockIdx.x - route * nrt * 25;
        rowTile = r2 / 25;
        jTile = r2 - rowTile * 25;
    }
    const int b0 = rowTile * GBM;
    const int j0 = jTile * GBN;

    __shared__ __align__(16) char smem[32768];
    ushort* As = (ushort*)smem;
    ushort* Bs = As + GBM * GBK;

    const int tid = threadIdx.x;
    const int l = tid & 63, w = tid >> 6;
    const int wm = w >> 1, wn = w & 1;

    f32x4 acc[4][4] = {};

    const ushort* Aptr = poseb + (size_t)route * PC_DIM;
    const ushort* Bptr = wt + (size_t)route * JDIM * PC_DIM;

    const int q4 = l >> 4;
    const int swz = l & 7;

    for (int k0 = 0; k0 < PC_DIM; k0 += GBK) {
        int f = tid;
#pragma unroll
        for (int i = 0; i < 4; i++, f += 256) {
            const int row = f >> 3;
            const int c = f & 7;
            const int qg = c ^ (row & 7);
            int ga = b0 + row; if (ga >= rows) ga = rows - 1;
            load_lds16(Aptr + (size_t)ga * ROW_IN + k0 + qg * 8, As + (size_t)f * 8);
            load_lds16(Bptr + (size_t)(j0 + row) * PC_DIM + k0 + qg * 8, Bs + (size_t)f * 8);
        }
        __syncthreads();

#pragma unroll
        for (int s = 0; s < 2; s++) {
            half8 af[4], bfg[4];
#pragma unroll
            for (int t = 0; t < 4; t++) {
                const int rowA = wm * 64 + t * 16 + (l & 15);
                const int rowB = wn * 64 + t * 16 + (l & 15);
                const int c = (s * 4 + q4) ^ swz;
                af[t]  = *(const half8*)(As + (size_t)(rowA * 8 + c) * 8);
                bfg[t] = *(const half8*)(Bs + (size_t)(rowB * 8 + c) * 8);
            }
#pragma unroll
            for (int mt = 0; mt < 4; mt++)
#pragma unroll
                for (int nt = 0; nt < 4; nt++)
                    acc[mt][nt] = __builtin_amdgcn_mfma_f32_16x16x32_f16(
                        af[mt], bfg[nt], acc[mt][nt], 0, 0, 0);
        }
        __syncthreads();
    }

    // Epilogue: per-wave LDS transpose, convert to fp16, 32B/lane stores.
    float* ep = (float*)smem + w * 16 * 68;
    const int erow = l >> 2;
    const int ec0  = (l & 3) * 16;
#pragma unroll
    for (int mt = 0; mt < 4; mt++) {
#pragma unroll
        for (int nt = 0; nt < 4; nt++)
#pragma unroll
            for (int i = 0; i < 4; i++)
                ep[((l >> 4) * 4 + i) * 68 + nt * 16 + (l & 15)] = acc[mt][nt][i];
        __syncthreads();
        const int grow = b0 + wm * 64 + mt * 16 + erow;
        if (grow < rows) {
            ushort t16[16];
#pragma unroll
            for (int t8 = 0; t8 < 4; t8++) {
                float4 v = *(float4*)&ep[erow * 68 + ec0 + t8 * 4];
                t16[t8*4+0]=f2h(v.x); t16[t8*4+1]=f2h(v.y);
                t16[t8*4+2]=f2h(v.z); t16[t8*4+3]=f2h(v.w);
            }
            ushort* dst = vote + (size_t)grow * VOTE_B + route * JDIM + j0 + wn * 64 + ec0;
            ((uint4*)dst)[0] = ((uint4*)t16)[0];
            ((uint4*)dst)[1] = ((uint4*)t16)[1];
        }
        __syncthreads();
    }
}

// ---------------- Kernel 2: fused routing ----------------
// Block = one batch elem, 448 threads (7 waves). Lane decomposition:
//   sub = l&15 -> v-dims [8*sub, 8*sub+8);  mg = l>>4;  m = wv + 7*mg (28 slots, 25 valid).
// Votes unpacked ONCE to 56 fp32 regs (VALU-throughput-bound kernel: the 5-pass
// fp16 re-unpack was ~35% of all VALU issue). Reductions: 4-step shfl over 16 lanes.
__global__ __launch_bounds__(448) void routing_kernel(
        const ushort* __restrict__ vote16,  // [chunk][7][25][128] fp16
        const float* __restrict__ act,      // (pre-offset)
        const float* __restrict__ gamma,
        const float* __restrict__ beta,
        const float* __restrict__ emb,      // [25,128]
        const float* __restrict__ bias,     // [25]
        float* __restrict__ out_logits,
        float* __restrict__ out_act,
        float* __restrict__ out_coef) {
    const int b = blockIdx.x;
    __shared__ float coef_s[N_ROUTES * KCLS];
    __shared__ float act_s[8];

    const int tid = threadIdx.x, l = tid & 63, wv = tid >> 6;   // 7 waves
    const int sub = l & 15, mg = l >> 4;
    const int m = wv + 7 * mg;                // 0..27
    const bool mv = (m < KCLS);

    if (tid < N_ROUTES) {
        float a = act[(size_t)b * N_ROUTES + tid];
        act_s[tid] = a;
        out_act[(size_t)b * N_ROUTES + tid] = a;
    }

    // Load votes (coalesced 16B) and unpack to fp32 ONCE.
    float vf[N_ROUTES][8];
    if (mv) {
        const uint4* vb = (const uint4*)(vote16 + (size_t)b * VOTE_B);  // n*400 + m*16 + sub
#pragma unroll
        for (int n = 0; n < N_ROUTES; n++) {
            uint4 q = vb[n * 400 + m * 16 + sub];
            float2 f0 = h2f2(q.x), f1 = h2f2(q.y), f2 = h2f2(q.z), f3 = h2f2(q.w);
            vf[n][0] = f0.x; vf[n][1] = f0.y; vf[n][2] = f1.x; vf[n][3] = f1.y;
            vf[n][4] = f2.x; vf[n][5] = f2.y; vf[n][6] = f3.x; vf[n][7] = f3.y;
        }
    } else {
#pragma unroll
        for (int n = 0; n < N_ROUTES; n++)
#pragma unroll
            for (int j = 0; j < 8; j++) vf[n][j] = 0.f;
    }
    const int mc = mv ? m : 24;

    float g[8], be[8];
    *(float4*)(g)      = *(const float4*)(gamma + 8 * sub);
    *(float4*)(g + 4)  = *(const float4*)(gamma + 8 * sub + 4);
    *(float4*)(be)     = *(const float4*)(beta  + 8 * sub);
    *(float4*)(be + 4) = *(const float4*)(beta  + 8 * sub + 4);
    __syncthreads();   // act_s ready

    const float scale = 0.088388347648318447f;    // 1/sqrt(128)
    float pose[8];

    auto update = [&](bool first) {
        float r[8];
#pragma unroll
        for (int j = 0; j < 8; j++) r[j] = 0.f;
#pragma unroll
        for (int n = 0; n < N_ROUTES; n++) {
            float c = first ? (act_s[n] * 0.04f) : (coef_s[n * KCLS + mc] * act_s[n]);
#pragma unroll
            for (int j = 0; j < 8; j++) r[j] += c * vf[n][j];
        }
        float S = 0.f, Q = 0.f;
#pragma unroll
        for (int j = 0; j < 8; j++) { S += r[j]; Q += r[j] * r[j]; }
#pragma unroll
        for (int o = 8; o; o >>= 1) {
            S += __shfl_xor(S, o);
            Q += __shfl_xor(Q, o);
        }
        float mean = S * 0.0078125f;
        float var  = Q * 0.0078125f - mean * mean;
        float rs   = rsqrtf(var + 1e-5f);
#pragma unroll
        for (int j = 0; j < 8; j++) pose[j] = (r[j] - mean) * rs * g[j] + be[j];
    };

    update(true);
    __syncthreads();   // (no coef dependency yet; keeps coef_s write ordering below safe)

    const int sgrp = tid >> 5, slane = tid & 31;   // 14 x 32-lane groups for softmax

    for (int it = 1; it < 3; it++) {
        // agreement: d[n] = <vote[n][m], pose[m]>
        float d[N_ROUTES];
#pragma unroll
        for (int n = 0; n < N_ROUTES; n++) {
            float t = 0.f;
#pragma unroll
            for (int j = 0; j < 8; j++) t += vf[n][j] * pose[j];
            d[n] = t;
        }
#pragma unroll
        for (int o = 8; o; o >>= 1)
#pragma unroll
            for (int n = 0; n < N_ROUTES; n++) d[n] += __shfl_xor(d[n], o);
        if (sub == 0 && mv) {
#pragma unroll
            for (int n = 0; n < N_ROUTES; n++) coef_s[n * KCLS + m] = d[n] * scale;
        }
        __syncthreads();
        // parallel softmax: group sgrp = route, lane slane = m
        if (sgrp < N_ROUTES) {
            float c = (slane < KCLS) ? coef_s[sgrp * KCLS + slane] : -1e30f;
            float mx = c;
#pragma unroll
            for (int o = 16; o; o >>= 1) mx = fmaxf(mx, __shfl_xor(mx, o, 32));
            float e = (slane < KCLS) ? expf(c - mx) : 0.f;
            float s = e;
#pragma unroll
            for (int o = 16; o; o >>= 1) s += __shfl_xor(s, o, 32);
            if (slane < KCLS) coef_s[sgrp * KCLS + slane] = e / s;
        }
        __syncthreads();
        update(false);
        if (it == 1) __syncthreads();   // coef_s reads done before next agree overwrites
    }

    // logits
    float e[8];
    *(float4*)(e)     = *(const float4*)(emb + mc * MC_DIM + 8 * sub);
    *(float4*)(e + 4) = *(const float4*)(emb + mc * MC_DIM + 8 * sub + 4);
    float dd = 0.f;
#pragma unroll
    for (int j = 0; j < 8; j++) dd += pose[j] * e[j];
#pragma unroll
    for (int o = 8; o; o >>= 1) dd += __shfl_xor(dd, o);
    if (sub == 0 && mv) out_logits[(size_t)b * KCLS + m] = dd + bias[m];

    if (tid < N_ROUTES * KCLS)
        out_coef[(size_t)b * (N_ROUTES * KCLS) + tid] = coef_s[tid];
}

// ---------------- launch ----------------
extern "C" void kernel_launch(void* const* d_in, const int* in_sizes, int n_in,
                              void* d_out, int out_size, void* d_ws, size_t ws_size,
                              hipStream_t stream) {
    const float* pose  = (const float*)d_in[0];
    const float* act   = (const float*)d_in[1];
    const float* w     = (const float*)d_in[2];
    const float* gamma = (const float*)d_in[3];
    const float* beta  = (const float*)d_in[4];
    const float* emb   = (const float*)d_in[5];
    const float* bias  = (const float*)d_in[6];

    float* out        = (float*)d_out;
    float* out_logits = out;
    float* out_act    = out + BATCH * KCLS;
    float* out_coef   = out + BATCH * KCLS + BATCH * N_ROUTES;

    // workspace: wt fp16 | poseb fp16 | vote fp16 (chunked)
    const size_t wt_bytes    = (size_t)N_ROUTES * JDIM * PC_DIM * 2;
    const size_t poseb_bytes = (size_t)BATCH * ROW_IN * 2;
    ushort* wt    = (ushort*)d_ws;
    ushort* poseb = (ushort*)((char*)d_ws + wt_bytes);
    ushort* voteh = (ushort*)((char*)d_ws + wt_bytes + poseb_bytes);

    size_t rem = ws_size > wt_bytes + poseb_bytes ? ws_size - wt_bytes - poseb_bytes : 0;
    size_t cap = rem / ((size_t)VOTE_B * 2);
    int chunk;
    if (cap >= (size_t)BATCH)  chunk = BATCH;
    else if (cap >= 128)       chunk = (int)(cap & ~(size_t)127);
    else                       chunk = (int)(cap > 0 ? cap : 1);

    conv_w<<<dim3(JDIM / 32, PC_DIM / 32, N_ROUTES), 256, 0, stream>>>(w, wt);
    const int n8 = BATCH * ROW_IN / 8;
    conv_pose<<<(n8 + 255) / 256, 256, 0, stream>>>(pose, poseb, n8);

    for (int b0 = 0; b0 < BATCH; b0 += chunk) {
        int rows = BATCH - b0 < chunk ? BATCH - b0 : chunk;
        int nRowTiles = (rows + GBM - 1) / GBM;
        vote_gemm_mfma<<<nRowTiles * N_ROUTES * 25, 256, 0, stream>>>(
            poseb + (size_t)b0 * ROW_IN, wt, voteh, rows);
        routing_kernel<<<rows, 448, 0, stream>>>(
            voteh,
            act + (size_t)b0 * N_ROUTES,
            gamma, beta, emb, bias,
            out_logits + (size_t)b0 * KCLS,
            out_act    + (size_t)b0 * N_ROUTES,
            out_coef   + (size_t)b0 * N_ROUTES * KCLS);
    }
}